// Round 3
// baseline (142.261 us; speedup 1.0000x reference)
//
#include <hip/hip_runtime.h>
#include <math.h>

// Problem constants
constexpr int T_LEN = 960000;   // samples per row
constexpr int NB    = 64;       // batch rows
constexpr int CHUNK = 128;      // output samples per thread
constexpr int WARM  = 128;      // warmup samples: pole decay 0.9251^128 ~ 4.7e-5
constexpr int CPR   = T_LEN / CHUNK;            // 7500 chunks per row
constexpr int BLOCK = 64;                       // ONE wave per block
constexpr int SEGS  = 64;                       // chunks handled per block
constexpr int BPR   = (CPR + SEGS - 1) / SEGS;  // 118 blocks per row (last partial)
constexpr int S     = 32;                       // slice length (samples)
constexpr int PITCH = 33;                       // LDS row pitch (floats), anti-conflict
constexpr int NW    = WARM / S;                 // 4 warm slices
constexpr int NM    = CHUNK / S;                // 4 main slices

__global__ __launch_bounds__(BLOCK)
void AudioPreprocessor_28080496181681_kernel(const float* __restrict__ x,
                                             const int* __restrict__ sr_ptr,
                                             float* __restrict__ out) {
    __shared__ float lds[SEGS * PITCH];         // 8448 B -> 19 blocks/CU (160 KB LDS)

    const int t   = threadIdx.x;
    const int row = blockIdx.x / BPR;
    const int bi  = blockIdx.x % BPR;
    const int c0  = bi * SEGS;                  // first chunk index of this block

    // --- biquad coefficients (double, cast to f32, mirroring numpy) ---
    const double sr    = (double)sr_ptr[0];
    const double w0    = 2.0 * M_PI * 1000.0 / sr;
    const double A     = pow(10.0, 3.0 / 40.0);
    const double alpha = sin(w0) / (2.0 * 0.707);
    const double a0d   = 1.0 + alpha / A;
    const float b0 = (float)((1.0 + alpha * A) / a0d);
    const float b1 = (float)((-2.0 * cos(w0)) / a0d);
    const float b2 = (float)((1.0 - alpha * A) / a0d);
    const float a1 = (float)((-2.0 * cos(w0)) / a0d);
    const float a2 = (float)((1.0 - alpha / A) / a0d);

    const float* __restrict__ xr   = x   + (size_t)row * T_LEN;
    float* __restrict__       orow = out + (size_t)row * T_LEN;

    // staging role: 8 lanes per segment, 8 segments per round, 8 rounds
    const int lseg = t >> 3;          // segment offset within each 8-seg round
    const int soff = (t & 7) * 4;     // float offset within slice

    // consumer role: thread t filters chunk (c0 + t)
    const int rb = t * PITCH;

    float x1 = 0.f, x2 = 0.f, y1 = 0.f, y2 = 0.f;
    const float g = 0.8f;

    for (int sl = 0; sl < NW + NM; ++sl) {
        const bool is_main = (sl >= NW);
        const int  t0 = is_main ? (sl - NW) * S : (sl * S - WARM); // slice start rel. chunk

        __syncthreads();  // buffer free (single-wave block: cheap)

        // ---- stage: global -> LDS, 8 rounds x 8 segments, full-line coalesced ----
        #pragma unroll
        for (int j = 0; j < 8; ++j) {
            const int seg = j * 8 + lseg;
            const int a   = (c0 + seg) * CHUNK + t0 + soff;   // index within row
            float4 v = make_float4(0.f, 0.f, 0.f, 0.f);
            if (a >= 0 && a + 4 <= T_LEN)                     // row-begin/end + tail guard
                v = *reinterpret_cast<const float4*>(xr + a);
            const int lb = seg * PITCH + soff;
            lds[lb + 0] = v.x; lds[lb + 1] = v.y; lds[lb + 2] = v.z; lds[lb + 3] = v.w;
        }
        __syncthreads();

        if (is_main) {
            // ---- consume own chunk: filter + gain + clamp, write back in place ----
            #pragma unroll
            for (int s = 0; s < S; ++s) {
                const float xv = lds[rb + s];
                const float yt = b0 * xv + b1 * x1 + b2 * x2 - a1 * y1 - a2 * y2;
                x2 = x1; x1 = xv; y2 = y1; y1 = yt;
                lds[rb + s] = fminf(fmaxf(yt * g, -1.f), 1.f);
            }
            __syncthreads();
            // ---- store: LDS -> global, full-line coalesced ----
            #pragma unroll
            for (int j = 0; j < 8; ++j) {
                const int seg = j * 8 + lseg;
                if (c0 + seg < CPR) {                          // active chunks only
                    const int a  = (c0 + seg) * CHUNK + t0 + soff;
                    const int lb = seg * PITCH + soff;
                    float4 v;
                    v.x = lds[lb + 0]; v.y = lds[lb + 1];
                    v.z = lds[lb + 2]; v.w = lds[lb + 3];
                    *reinterpret_cast<float4*>(orow + a) = v;
                }
            }
        } else {
            // ---- warmup consume: advance filter state only ----
            #pragma unroll
            for (int s = 0; s < S; ++s) {
                const float xv = lds[rb + s];
                const float yt = b0 * xv + b1 * x1 + b2 * x2 - a1 * y1 - a2 * y2;
                x2 = x1; x1 = xv; y2 = y1; y1 = yt;
            }
        }
    }
}

extern "C" void kernel_launch(void* const* d_in, const int* in_sizes, int n_in,
                              void* d_out, int out_size, void* d_ws, size_t ws_size,
                              hipStream_t stream) {
    const float* x   = (const float*)d_in[0];
    const int*   sr  = (const int*)d_in[1];
    float*       out = (float*)d_out;

    const int grid = NB * BPR;   // 64 rows x 118 blocks = 7552 blocks
    AudioPreprocessor_28080496181681_kernel<<<grid, BLOCK, 0, stream>>>(x, sr, out);
}

// Round 4
// 95.319 us; speedup vs baseline: 1.4925x; 1.4925x over previous
//
#include <hip/hip_runtime.h>
#include <math.h>

// Problem constants
constexpr int T_LEN = 960000;    // samples per row
constexpr int NB    = 64;        // batch rows
constexpr int WARM  = 128;       // warmup samples: pole decay 0.9251^128 ~ 4.7e-5
constexpr int MAIN  = 1920;      // output samples per wave-tile
constexpr int TILE  = WARM + MAIN;          // 2048 samples = 8 groups x 64 lanes x 4
constexpr int TPR   = T_LEN / MAIN;         // 500 tiles per row (exact)
constexpr int WPB   = 4;                    // waves per block
constexpr int BLOCK = 64 * WPB;

struct M2 { float m00, m01, m10, m11; };    // 2x2 matrix

static __device__ inline M2 mm(const M2& P, const M2& Q) {
    M2 r;
    r.m00 = P.m00 * Q.m00 + P.m01 * Q.m10;
    r.m01 = P.m00 * Q.m01 + P.m01 * Q.m11;
    r.m10 = P.m10 * Q.m00 + P.m11 * Q.m10;
    r.m11 = P.m10 * Q.m01 + P.m11 * Q.m11;
    return r;
}

static __device__ inline float rfl(float v) {
    return __uint_as_float(__builtin_amdgcn_readfirstlane(__float_as_uint(v)));
}

__global__ __launch_bounds__(BLOCK)
void AudioPreprocessor_28080496181681_kernel(const float* __restrict__ x,
                                             const int* __restrict__ sr_ptr,
                                             float* __restrict__ out) {
    const int lane = threadIdx.x & 63;
    const int wid  = blockIdx.x * WPB + (threadIdx.x >> 6);  // global wave id = tile id
    const int row  = wid / TPR;
    const int tw   = wid % TPR;

    // --- biquad coefficients (double, cast to f32, mirroring numpy) ---
    const double srd   = (double)sr_ptr[0];
    const double w0    = 2.0 * M_PI * 1000.0 / srd;
    const double Ag    = pow(10.0, 3.0 / 40.0);
    const double alpha = sin(w0) / (2.0 * 0.707);
    const double a0d   = 1.0 + alpha / Ag;
    const float b0 = rfl((float)((1.0 + alpha * Ag) / a0d));
    const float b1 = rfl((float)((-2.0 * cos(w0)) / a0d));
    const float b2 = rfl((float)((1.0 - alpha * Ag) / a0d));
    const float a1 = rfl((float)((-2.0 * cos(w0)) / a0d));
    const float a2 = rfl((float)((1.0 - alpha / Ag) / a0d));

    // --- transition-matrix powers (uniform across lanes) ---
    M2 A1 = { -a1, -a2, 1.f, 0.f };
    M2 A2 = mm(A1, A1);
    M2 A3 = mm(A2, A1);
    M2 M[6];                    // A^(4*2^k), k=0..5
    M[0] = mm(A2, A2);          // A^4
    #pragma unroll
    for (int k = 1; k < 6; ++k) M[k] = mm(M[k - 1], M[k - 1]);
    const M2 A4 = M[0];

    const float* __restrict__ xr   = x   + (size_t)row * T_LEN;
    float* __restrict__       orow = out + (size_t)row * T_LEN;
    const int base = tw * MAIN - WARM;      // tile start sample (may be <0 for tw==0)

    // --- issue all 8 coalesced loads up-front ---
    float4 v[8];
    #pragma unroll
    for (int j = 0; j < 8; ++j) {
        const int a = base + (j * 64 + lane) * 4;
        if (a >= 0) v[j] = *reinterpret_cast<const float4*>(xr + a);
        else        v[j] = make_float4(0.f, 0.f, 0.f, 0.f);
    }

    float cy0 = 0.f, cy1 = 0.f;   // carry: state (y_{t-1}, y_{t-2}) entering next group
    float pxw = 0.f, pxz = 0.f;   // last two x of previous group (lane 63)
    const float g = 0.8f;

    #pragma unroll
    for (int j = 0; j < 8; ++j) {
        const float4 c = v[j];

        // previous-segment inputs: lane i-1's (z,w); lane 0 from prev group carry
        float xm1 = __shfl_up(c.w, 1);
        float xm2 = __shfl_up(c.z, 1);
        if (lane == 0) { xm1 = pxw; xm2 = pxz; }

        // local pass from zero state -> zero-state outputs y*z and d=(y3,y2)
        const float u0 = b0 * c.x + b1 * xm1 + b2 * xm2;
        const float y0z = u0;
        const float u1 = b0 * c.y + b1 * c.x + b2 * xm1;
        const float y1z = u1 - a1 * y0z;
        const float u2 = b0 * c.z + b1 * c.y + b2 * c.x;
        const float y2z = u2 - a1 * y1z - a2 * y0z;
        const float u3 = b0 * c.w + b1 * c.z + b2 * c.y;
        const float y3z = u3 - a1 * y2z - a2 * y1z;

        float s0 = y3z, s1 = y2z;
        // seed: fold carry into lane 0's segment:  d0 += A^4 * carry
        if (lane == 0) {
            s0 += A4.m00 * cy0 + A4.m01 * cy1;
            s1 += A4.m10 * cy0 + A4.m11 * cy1;
        }

        // Kogge-Stone inclusive scan of affine maps (uniform matrix powers)
        #pragma unroll
        for (int k = 0; k < 6; ++k) {
            const int del = 1 << k;
            float t0 = __shfl_up(s0, del);
            float t1 = __shfl_up(s1, del);
            const bool ok = (lane >= del);
            t0 = ok ? t0 : 0.f;
            t1 = ok ? t1 : 0.f;
            s0 += M[k].m00 * t0 + M[k].m01 * t1;
            s1 += M[k].m10 * t0 + M[k].m11 * t1;
        }

        // entering state per lane = exclusive scan
        float e0 = __shfl_up(s0, 1);
        float e1 = __shfl_up(s1, 1);
        if (lane == 0) { e0 = cy0; e1 = cy1; }

        // carry to next group = inclusive result of lane 63
        cy0 = __shfl(s0, 63);
        cy1 = __shfl(s1, 63);
        pxw = __shfl(c.w, 63);
        pxz = __shfl(c.z, 63);

        // corrected outputs: y_k = y_kz + (A^{k+1})[0,:] . enter
        float o0 = y0z + A1.m00 * e0 + A1.m01 * e1;
        float o1 = y1z + A2.m00 * e0 + A2.m01 * e1;
        float o2 = y2z + A3.m00 * e0 + A3.m01 * e1;
        float o3 = y3z + A4.m00 * e0 + A4.m01 * e1;

        // gain + clamp
        o0 = fminf(fmaxf(o0 * g, -1.f), 1.f);
        o1 = fminf(fmaxf(o1 * g, -1.f), 1.f);
        o2 = fminf(fmaxf(o2 * g, -1.f), 1.f);
        o3 = fminf(fmaxf(o3 * g, -1.f), 1.f);

        // store (skip warmup region: group 0, lanes 0-31)
        if (!(j == 0 && lane < 32)) {
            const int a = base + (j * 64 + lane) * 4;
            *reinterpret_cast<float4*>(orow + a) = make_float4(o0, o1, o2, o3);
        }
    }
}

extern "C" void kernel_launch(void* const* d_in, const int* in_sizes, int n_in,
                              void* d_out, int out_size, void* d_ws, size_t ws_size,
                              hipStream_t stream) {
    const float* x   = (const float*)d_in[0];
    const int*   sr  = (const int*)d_in[1];
    float*       out = (float*)d_out;

    const int waves = NB * TPR;          // 32000 wave-tiles
    const int grid  = waves / WPB;       // 8000 blocks of 256 threads
    AudioPreprocessor_28080496181681_kernel<<<grid, BLOCK, 0, stream>>>(x, sr, out);
}

// Round 6
// 82.213 us; speedup vs baseline: 1.7304x; 1.1594x over previous
//
#include <hip/hip_runtime.h>
#include <math.h>

// Problem constants
constexpr int T_LEN = 960000;    // samples per row
constexpr int NB    = 64;        // batch rows
constexpr int WARM  = 128;       // warmup samples: pole decay 0.9251^128 ~ 4.7e-5
constexpr int MAIN  = 3200;      // output samples per wave-tile (3200 | 960000, ≡128 mod 256)
constexpr int TILE  = WARM + MAIN;   // 3328 = 13 groups x 64 lanes x 4
constexpr int NG    = TILE / 256;    // 13 groups
constexpr int TPR   = T_LEN / MAIN;  // 300 tiles per row (exact)
constexpr int WPB   = 4;             // waves per block
constexpr int BLOCK = 64 * WPB;

typedef float f32x4 __attribute__((ext_vector_type(4)));  // native vector for NT store

struct M2 { float m00, m01, m10, m11; };    // 2x2 matrix

static __device__ inline float rfl(float v) {
    return __uint_as_float(__builtin_amdgcn_readfirstlane(__float_as_uint(v)));
}

static __device__ inline M2 mm(const M2& P, const M2& Q) {
    M2 r;
    r.m00 = P.m00 * Q.m00 + P.m01 * Q.m10;
    r.m01 = P.m00 * Q.m01 + P.m01 * Q.m11;
    r.m10 = P.m10 * Q.m00 + P.m11 * Q.m10;
    r.m11 = P.m10 * Q.m01 + P.m11 * Q.m11;
    return r;
}

static __device__ inline M2 srfl(const M2& P) {   // hoist to SGPRs (wave-uniform)
    M2 r;
    r.m00 = rfl(P.m00); r.m01 = rfl(P.m01);
    r.m10 = rfl(P.m10); r.m11 = rfl(P.m11);
    return r;
}

__global__ __launch_bounds__(BLOCK)
void AudioPreprocessor_28080496181681_kernel(const float* __restrict__ x,
                                             const int* __restrict__ sr_ptr,
                                             float* __restrict__ out) {
    const int lane = threadIdx.x & 63;
    const int wid  = blockIdx.x * WPB + (threadIdx.x >> 6);  // global wave id = tile id
    const int row  = wid / TPR;
    const int tw   = wid % TPR;

    // --- biquad coefficients (double, cast to f32, mirroring numpy; SGPR-hoisted) ---
    const double srd   = (double)sr_ptr[0];
    const double w0    = 2.0 * M_PI * 1000.0 / srd;
    const double Ag    = pow(10.0, 3.0 / 40.0);
    const double alpha = sin(w0) / (2.0 * 0.707);
    const double a0d   = 1.0 + alpha / Ag;
    const float b0 = rfl((float)((1.0 + alpha * Ag) / a0d));
    const float b1 = rfl((float)((-2.0 * cos(w0)) / a0d));
    const float b2 = rfl((float)((1.0 - alpha * Ag) / a0d));
    const float a1 = rfl((float)((-2.0 * cos(w0)) / a0d));
    const float a2 = rfl((float)((1.0 - alpha / Ag) / a0d));

    // --- transition-matrix powers (wave-uniform, SGPR-hoisted) ---
    M2 A1 = srfl({ -a1, -a2, 1.f, 0.f });
    M2 A2 = srfl(mm(A1, A1));
    M2 A3 = srfl(mm(A2, A1));
    M2 M[6];                          // A^(4*2^k), k=0..5
    M[0] = srfl(mm(A2, A2));          // A^4
    #pragma unroll
    for (int k = 1; k < 6; ++k) M[k] = srfl(mm(M[k - 1], M[k - 1]));
    const M2 A4 = M[0];

    const float* __restrict__ xr   = x   + (size_t)row * T_LEN;
    float* __restrict__       orow = out + (size_t)row * T_LEN;
    const int base = tw * MAIN - WARM;      // tile start sample (<0 only for tw==0)

    // --- issue all coalesced loads up-front (each instr = 8 full 128B lines) ---
    float4 v[NG];
    #pragma unroll
    for (int j = 0; j < NG; ++j) {
        const int a = base + (j * 64 + lane) * 4;
        if (a >= 0) v[j] = *reinterpret_cast<const float4*>(xr + a);
        else        v[j] = make_float4(0.f, 0.f, 0.f, 0.f);
    }

    float cy0 = 0.f, cy1 = 0.f;   // carry: state (y_{t-1}, y_{t-2}) entering next group
    float pxw = 0.f, pxz = 0.f;   // last two x of previous group (lane 63)
    const float g = 0.8f;

    #pragma unroll
    for (int j = 0; j < NG; ++j) {
        const float4 c = v[j];

        // previous-segment inputs: lane i-1's (z,w); lane 0 from prev group carry
        float xm1 = __shfl_up(c.w, 1);
        float xm2 = __shfl_up(c.z, 1);
        if (lane == 0) { xm1 = pxw; xm2 = pxz; }

        // local pass from zero state -> zero-state outputs
        const float y0z = b0 * c.x + b1 * xm1 + b2 * xm2;
        const float y1z = b0 * c.y + b1 * c.x + b2 * xm1 - a1 * y0z;
        const float y2z = b0 * c.z + b1 * c.y + b2 * c.x - a1 * y1z - a2 * y0z;
        const float y3z = b0 * c.w + b1 * c.z + b2 * c.y - a1 * y2z - a2 * y1z;

        float s0 = y3z, s1 = y2z;
        // seed: fold carry into lane 0's segment: d0 += A^4 * carry
        if (lane == 0) {
            s0 += A4.m00 * cy0 + A4.m01 * cy1;
            s1 += A4.m10 * cy0 + A4.m11 * cy1;
        }

        // Kogge-Stone inclusive scan of affine maps (uniform matrix powers)
        #pragma unroll
        for (int k = 0; k < 6; ++k) {
            const int del = 1 << k;
            float t0 = __shfl_up(s0, del);
            float t1 = __shfl_up(s1, del);
            const bool ok = (lane >= del);
            t0 = ok ? t0 : 0.f;
            t1 = ok ? t1 : 0.f;
            s0 += M[k].m00 * t0 + M[k].m01 * t1;
            s1 += M[k].m10 * t0 + M[k].m11 * t1;
        }

        // entering state per lane = exclusive scan
        float e0 = __shfl_up(s0, 1);
        float e1 = __shfl_up(s1, 1);
        if (lane == 0) { e0 = cy0; e1 = cy1; }

        // carry to next group = inclusive result of lane 63
        cy0 = __shfl(s0, 63);
        cy1 = __shfl(s1, 63);
        pxw = __shfl(c.w, 63);
        pxz = __shfl(c.z, 63);

        // corrected outputs: y_k = y_kz + (A^{k+1})[0,:] . enter; gain + clamp
        f32x4 o;
        o.x = fminf(fmaxf((y0z + A1.m00 * e0 + A1.m01 * e1) * g, -1.f), 1.f);
        o.y = fminf(fmaxf((y1z + A2.m00 * e0 + A2.m01 * e1) * g, -1.f), 1.f);
        o.z = fminf(fmaxf((y2z + A3.m00 * e0 + A3.m01 * e1) * g, -1.f), 1.f);
        o.w = fminf(fmaxf((y3z + A4.m00 * e0 + A4.m01 * e1) * g, -1.f), 1.f);

        // store (skip warmup region: group 0, lanes 0-31); non-temporal (never re-read)
        if (!(j == 0 && lane < 32)) {
            const int a = base + (j * 64 + lane) * 4;
            __builtin_nontemporal_store(o, reinterpret_cast<f32x4*>(orow + a));
        }
    }
}

extern "C" void kernel_launch(void* const* d_in, const int* in_sizes, int n_in,
                              void* d_out, int out_size, void* d_ws, size_t ws_size,
                              hipStream_t stream) {
    const float* x   = (const float*)d_in[0];
    const int*   sr  = (const int*)d_in[1];
    float*       out = (float*)d_out;

    const int waves = NB * TPR;          // 19200 wave-tiles
    const int grid  = waves / WPB;       // 4800 blocks of 256 threads
    AudioPreprocessor_28080496181681_kernel<<<grid, BLOCK, 0, stream>>>(x, sr, out);
}